// Round 2
// baseline (105.773 us; speedup 1.0000x reference)
//
#include <hip/hip_runtime.h>
#include <hip/hip_bf16.h>

typedef __bf16 bf16_t;
typedef __attribute__((ext_vector_type(8))) __bf16 bf16x8;
typedef __attribute__((ext_vector_type(4))) float f32x4;

#define BATCH 16384
#define KDIM 1152
#define NDIM 1152
#define BM 128
#define BN 128
#define BK 64
#define NKT (KDIM / BK) /* 18 */

__device__ __forceinline__ void gload_lds16(const void* g, void* l) {
    __builtin_amdgcn_global_load_lds(
        (const __attribute__((address_space(1))) void*)g,
        (__attribute__((address_space(3))) void*)l, 16, 0, 0);
}

__device__ __forceinline__ void cvt_store(char* dst, const f32x4 a, const f32x4 b) {
    bf16x8 p;
    p[0] = (__bf16)a[0]; p[1] = (__bf16)a[1]; p[2] = (__bf16)a[2]; p[3] = (__bf16)a[3];
    p[4] = (__bf16)b[0]; p[5] = (__bf16)b[1]; p[6] = (__bf16)b[2]; p[7] = (__bf16)b[3];
    *(bf16x8*)dst = p;
}

// Fold the 9 conv taps into the effective 3x3 (a,bb) cells, emit bf16 Weff in a
// per-n-tile, per-k-tile, XOR-swizzled layout so GEMM's B staging is a linear
// global_load_lds and its ds_read_b128 is bank-conflict-light.
// Element (n,k): ntile = n>>7, ktile = k>>6, offset = (n&127)*64 + ((k&63) ^ (((n&127)&7)<<3))
__global__ void build_wb(const float* __restrict__ W,
                         const float* __restrict__ bvec,
                         bf16_t* __restrict__ Bm,
                         float* __restrict__ bias)
{
    const int t = blockIdx.x * blockDim.x + threadIdx.x;
    if (t < NDIM) {
        const int o = t / 9, p = t - o * 9;
        bias[t] = bvec[p * 128 + o];
    }
    const int c = t & 127;
    const int o = (t >> 7) & 127;
    const int p = t >> 14;
    if (p >= 9) return;
    const int r = p / 3, cc = p - r * 3;
    float eff[3][3] = {{0.f,0.f,0.f},{0.f,0.f,0.f},{0.f,0.f,0.f}};
    const float* w = W + (size_t)((p * 128 + o) * 128 + c) * 9;
    #pragma unroll
    for (int i = 0; i < 3; ++i) {
        const int a = (2 + r + i) / 3;
        #pragma unroll
        for (int j = 0; j < 3; ++j) {
            const int bb = (2 + cc + j) / 3;
            eff[a][bb] += w[i * 3 + j];
        }
    }
    const int n = o * 9 + p;
    const int ntile = n >> 7, nin = n & 127;
    bf16_t* blk = Bm + (size_t)ntile * (KDIM * 128);
    #pragma unroll
    for (int a = 0; a < 3; ++a)
        #pragma unroll
        for (int bb = 0; bb < 3; ++bb) {
            const int k = c * 9 + a * 3 + bb;
            const int kt = k >> 6, kin = k & 63;
            blk[kt * 8192 + nin * 64 + (kin ^ ((nin & 7) << 3))] = (bf16_t)eff[a][bb];
        }
}

// GEMM: out[M=16384, N=1152] = X[M,K=1152](fp32->bf16) * Weff[K,N](bf16) + bias
// 128x128 tile, BK=64, 4 waves (2x2), 4x4 16x16x32 bf16 MFMA frags per wave.
// A: reg-staged fp32->bf16 with XOR-swizzled ds_write_b128.
// B: global_load_lds (16B) from pre-swizzled panel (linear dest, rule #21).
__launch_bounds__(256, 2)
__global__ void ind_gemm(const float* __restrict__ X,
                         const bf16_t* __restrict__ Bm,
                         const float* __restrict__ bias,
                         float* __restrict__ out)
{
    __shared__ char As[2][BM * BK * 2]; // 16 KB each
    __shared__ char Bs[2][BN * BK * 2]; // 16 KB each

    const int tid = threadIdx.x;
    const int lane = tid & 63;
    const int wid = tid >> 6;
    const int wr = wid >> 1;
    const int wc = wid & 1;

    // XCD-aware swizzle (1152 % 8 == 0 -> simple form is bijective);
    // within an XCD, consecutive blocks share one m-panel across all 9 n-tiles.
    const int bid = blockIdx.x;
    const int swz = (bid & 7) * 144 + (bid >> 3);
    const int mt = swz / 9;
    const int nt = swz - mt * 9;
    const int m0 = mt * BM;

    // A staging: thread loads 16 floats of row (tid/4) at col (tid&3)*16
    const int arow = tid >> 2;
    const int acol = (tid & 3) * 16;
    const float* ag0 = X + (size_t)(m0 + arow) * KDIM + acol;
    const float* ag1 = ag0 + (size_t)64 * KDIM;

    const int arow1 = arow + 64;
    const int aw0a = arow * 128 + ((acol * 2) ^ ((arow & 7) << 4));
    const int aw0b = arow * 128 + ((acol * 2 + 16) ^ ((arow & 7) << 4));
    const int aw1a = arow1 * 128 + ((acol * 2) ^ ((arow1 & 7) << 4));
    const int aw1b = arow1 * 128 + ((acol * 2 + 16) ^ ((arow1 & 7) << 4));

    const char* bpanel = (const char*)(Bm + (size_t)nt * (KDIM * 128));
    const int bg_off = tid * 16;
    const int bl_off = wid * 1024; // wave-uniform LDS base

    f32x4 acc[4][4];
    #pragma unroll
    for (int i = 0; i < 4; ++i)
        #pragma unroll
        for (int j = 0; j < 4; ++j)
            acc[i][j] = (f32x4){0.f, 0.f, 0.f, 0.f};

    f32x4 ra[8];

    // ---- prologue: stage kt = 0 into buffer 0 ----
    #pragma unroll
    for (int q = 0; q < 4; ++q) ra[q] = *(const f32x4*)(ag0 + q * 4);
    #pragma unroll
    for (int q = 0; q < 4; ++q) ra[4 + q] = *(const f32x4*)(ag1 + q * 4);
    #pragma unroll
    for (int q = 0; q < 4; ++q)
        gload_lds16(bpanel + q * 4096 + bg_off, &Bs[0][q * 4096 + bl_off]);
    cvt_store(&As[0][aw0a], ra[0], ra[1]);
    cvt_store(&As[0][aw0b], ra[2], ra[3]);
    cvt_store(&As[0][aw1a], ra[4], ra[5]);
    cvt_store(&As[0][aw1b], ra[6], ra[7]);
    __syncthreads();

    #pragma unroll 1
    for (int kt = 0; kt < NKT; ++kt) {
        const int cur = kt & 1;
        if (kt + 1 < NKT) {
            const int koff = (kt + 1) * BK;
            #pragma unroll
            for (int q = 0; q < 4; ++q) ra[q] = *(const f32x4*)(ag0 + koff + q * 4);
            #pragma unroll
            for (int q = 0; q < 4; ++q) ra[4 + q] = *(const f32x4*)(ag1 + koff + q * 4);
            const char* gb = bpanel + (kt + 1) * 16384;
            #pragma unroll
            for (int q = 0; q < 4; ++q)
                gload_lds16(gb + q * 4096 + bg_off, &Bs[cur ^ 1][q * 4096 + bl_off]);
        }
        const char* Ab = &As[cur][0];
        const char* Bb = &Bs[cur][0];
        #pragma unroll
        for (int kk = 0; kk < 2; ++kk) {
            const int kb = kk * 64 + ((lane >> 4) << 4); // byte offset of this lane's 8-k group
            bf16x8 af[4], bfr[4];
            #pragma unroll
            for (int mi = 0; mi < 4; ++mi) {
                const int row = wr * 64 + mi * 16 + (lane & 15);
                af[mi] = *(const bf16x8*)(Ab + row * 128 + (kb ^ ((row & 7) << 4)));
            }
            #pragma unroll
            for (int ni = 0; ni < 4; ++ni) {
                const int row = wc * 64 + ni * 16 + (lane & 15);
                bfr[ni] = *(const bf16x8*)(Bb + row * 128 + (kb ^ ((row & 7) << 4)));
            }
            #pragma unroll
            for (int mi = 0; mi < 4; ++mi)
                #pragma unroll
                for (int ni = 0; ni < 4; ++ni)
                    acc[mi][ni] = __builtin_amdgcn_mfma_f32_16x16x32_bf16(
                        af[mi], bfr[ni], acc[mi][ni], 0, 0, 0);
        }
        if (kt + 1 < NKT) {
            char* An = &As[cur ^ 1][0];
            cvt_store(An + aw0a, ra[0], ra[1]);
            cvt_store(An + aw0b, ra[2], ra[3]);
            cvt_store(An + aw1a, ra[4], ra[5]);
            cvt_store(An + aw1b, ra[6], ra[7]);
            __syncthreads();
        }
    }

    // ---- epilogue: C/D layout col=lane&15, row=(lane>>4)*4+reg ----
    const int n0 = nt * BN;
    const int orow = (lane >> 4) << 2;
    const int ocol = lane & 15;
    #pragma unroll
    for (int ni = 0; ni < 4; ++ni) {
        const int gn = n0 + wc * 64 + ni * 16 + ocol;
        const float bv = bias[gn];
        #pragma unroll
        for (int mi = 0; mi < 4; ++mi) {
            const int gm = m0 + wr * 64 + mi * 16 + orow;
            float* po = out + (size_t)gm * NDIM + gn;
            #pragma unroll
            for (int r = 0; r < 4; ++r)
                po[(size_t)r * NDIM] = acc[mi][ni][r] + bv;
        }
    }
}

extern "C" void kernel_launch(void* const* d_in, const int* in_sizes, int n_in,
                              void* d_out, int out_size, void* d_ws, size_t ws_size,
                              hipStream_t stream)
{
    const float* x  = (const float*)d_in[0];
    const float* W  = (const float*)d_in[1];
    const float* bv = (const float*)d_in[2];
    float* out = (float*)d_out;

    bf16_t* Bm  = (bf16_t*)d_ws;                                   // 9*1152*128 bf16 = 2.65 MB
    float* bias = (float*)((char*)d_ws + (size_t)9 * KDIM * 128 * sizeof(bf16_t));

    build_wb<<<576, 256, 0, stream>>>(W, bv, Bm, bias);
    ind_gemm<<<1152, 256, 0, stream>>>(x, Bm, bias, out);
}

// Round 3
// 103.092 us; speedup vs baseline: 1.0260x; 1.0260x over previous
//
#include <hip/hip_runtime.h>
#include <hip/hip_bf16.h>

typedef __bf16 bf16_t;
typedef __attribute__((ext_vector_type(8))) __bf16 bf16x8;
typedef __attribute__((ext_vector_type(4))) __bf16 bf16x4;
typedef __attribute__((ext_vector_type(4))) float f32x4;

#define BATCH 16384
#define KDIM 1152
#define NDIM 1152
#define BM 128
#define BN 128
#define BK 32
#define NKT (KDIM / BK) /* 36 */

__device__ __forceinline__ void gload_lds16(const void* g, void* l) {
    __builtin_amdgcn_global_load_lds(
        (const __attribute__((address_space(1))) void*)g,
        (__attribute__((address_space(3))) void*)l, 16, 0, 0);
}

__device__ __forceinline__ void cvt_store8(char* dst, const f32x4 a) {
    bf16x4 p;
    p[0] = (__bf16)a[0]; p[1] = (__bf16)a[1]; p[2] = (__bf16)a[2]; p[3] = (__bf16)a[3];
    *(bf16x4*)dst = p;
}

// Fold the 9 conv taps into effective 3x3 (a,bb) cells; emit bf16 Weff panels in
// k-group-major order so GEMM's B staging is a LINEAR global_load_lds:
//   per n-tile: unit index = kt*512 + g*128 + n   (16B units, g = (k>>3)&3, kt = k>>5)
//   bf16 index = kt*4096 + g*1024 + n*8 + (k&7)
__global__ void build_wb(const float* __restrict__ W,
                         const float* __restrict__ bvec,
                         bf16_t* __restrict__ Bm,
                         float* __restrict__ bias)
{
    const int t = blockIdx.x * blockDim.x + threadIdx.x;
    if (t < NDIM) {
        const int o = t / 9, p = t - o * 9;
        bias[t] = bvec[p * 128 + o];
    }
    const int c = t & 127;
    const int o = (t >> 7) & 127;
    const int p = t >> 14;
    if (p >= 9) return;
    const int r = p / 3, cc = p - r * 3;
    float eff[3][3] = {{0.f,0.f,0.f},{0.f,0.f,0.f},{0.f,0.f,0.f}};
    const float* w = W + (size_t)((p * 128 + o) * 128 + c) * 9;
    #pragma unroll
    for (int i = 0; i < 3; ++i) {
        const int a = (2 + r + i) / 3;
        #pragma unroll
        for (int j = 0; j < 3; ++j) {
            const int bb = (2 + cc + j) / 3;
            eff[a][bb] += w[i * 3 + j];
        }
    }
    const int n = o * 9 + p;
    const int ntile = n >> 7, nin = n & 127;
    bf16_t* blk = Bm + (size_t)ntile * (KDIM * 128);
    #pragma unroll
    for (int a = 0; a < 3; ++a)
        #pragma unroll
        for (int bb = 0; bb < 3; ++bb) {
            const int k = c * 9 + a * 3 + bb;
            blk[(k >> 5) * 4096 + ((k >> 3) & 3) * 1024 + nin * 8 + (k & 7)]
                = (bf16_t)eff[a][bb];
        }
}

// GEMM: out[16384,1152] = X(fp32->bf16) * Weff(bf16) + bias.
// 128x128 tile, BK=32, dbuf, 4 waves (2x2), 4x4 16x16x32 MFMA frags/wave.
// LDS: k-group-major [g][row] 16B units -> conflict-free reads & writes, 32KB total
// -> 4 blocks/CU (16 waves/CU) for latency hiding.
__launch_bounds__(256, 4)
__global__ void ind_gemm(const float* __restrict__ X,
                         const bf16_t* __restrict__ Bm,
                         const float* __restrict__ bias,
                         float* __restrict__ out)
{
    __shared__ char As[2][4 * 128 * 16]; // 8 KB each
    __shared__ char Bs[2][4 * 128 * 16]; // 8 KB each

    const int tid = threadIdx.x;
    const int lane = tid & 63;
    const int wid = tid >> 6;
    const int wr = wid >> 1;
    const int wc = wid & 1;

    // XCD-aware swizzle (1152 % 8 == 0 -> bijective); within an XCD consecutive
    // blocks share one m-panel across the 9 n-tiles (L2/L3 reuse of X).
    const int bid = blockIdx.x;
    const int swz = (bid & 7) * 144 + (bid >> 3);
    const int mt = swz / 9;
    const int nt = swz - mt * 9;
    const int m0 = mt * BM;

    // A: thread t loads 16B (4 floats) of row (t>>3)+q*32 at float-col (t&7)*4.
    // Each 8-lane group = one full 128B line -> perfectly coalesced.
    const int arow = tid >> 3;
    const int acol = (tid & 7) * 4;
    const float* ag = X + (size_t)(m0 + arow) * KDIM + acol;
    // LDS dest: g = acol>>3, byte = g*2048 + row*16 + (acol&4)*2
    const int awbase = (acol >> 3) * 2048 + arow * 16 + (acol & 4) * 2;

    const char* bpanel = (const char*)(Bm + (size_t)nt * (KDIM * 128));

    // frag read base: lane's k-group + row-within-16
    const int fg = (lane >> 4) * 2048 + (lane & 15) * 16;

    f32x4 acc[4][4];
    #pragma unroll
    for (int i = 0; i < 4; ++i)
        #pragma unroll
        for (int j = 0; j < 4; ++j)
            acc[i][j] = (f32x4){0.f, 0.f, 0.f, 0.f};

    f32x4 ra[4];

    // ---- prologue: stage kt = 0 into buffer 0 ----
    #pragma unroll
    for (int q = 0; q < 4; ++q)
        ra[q] = *(const f32x4*)(ag + (size_t)q * 32 * KDIM);
    gload_lds16(bpanel + tid * 16,        &Bs[0][wid * 1024]);
    gload_lds16(bpanel + 4096 + tid * 16, &Bs[0][4096 + wid * 1024]);
    #pragma unroll
    for (int q = 0; q < 4; ++q)
        cvt_store8(&As[0][awbase + q * 512], ra[q]);
    __syncthreads();

    #pragma unroll 1
    for (int kt = 0; kt < NKT; ++kt) {
        const int cur = kt & 1;
        if (kt + 1 < NKT) {
            const int koff = (kt + 1) * BK;
            #pragma unroll
            for (int q = 0; q < 4; ++q)
                ra[q] = *(const f32x4*)(ag + (size_t)q * 32 * KDIM + koff);
            const char* gb = bpanel + (kt + 1) * 8192;
            gload_lds16(gb + tid * 16,        &Bs[cur ^ 1][wid * 1024]);
            gload_lds16(gb + 4096 + tid * 16, &Bs[cur ^ 1][4096 + wid * 1024]);
        }
        const char* Ab = &As[cur][0];
        const char* Bb = &Bs[cur][0];
        bf16x8 af[4], bfr[4];
        #pragma unroll
        for (int mi = 0; mi < 4; ++mi)
            af[mi] = *(const bf16x8*)(Ab + fg + (wr * 64 + mi * 16) * 16);
        #pragma unroll
        for (int ni = 0; ni < 4; ++ni)
            bfr[ni] = *(const bf16x8*)(Bb + fg + (wc * 64 + ni * 16) * 16);
        #pragma unroll
        for (int mi = 0; mi < 4; ++mi)
            #pragma unroll
            for (int ni = 0; ni < 4; ++ni)
                acc[mi][ni] = __builtin_amdgcn_mfma_f32_16x16x32_bf16(
                    af[mi], bfr[ni], acc[mi][ni], 0, 0, 0);
        if (kt + 1 < NKT) {
            char* An = &As[cur ^ 1][0];
            #pragma unroll
            for (int q = 0; q < 4; ++q)
                cvt_store8(An + awbase + q * 512, ra[q]);
            __syncthreads();
        }
    }

    // ---- epilogue: C/D layout col=lane&15, row=(lane>>4)*4+reg ----
    const int n0 = nt * BN;
    const int orow = (lane >> 4) << 2;
    const int ocol = lane & 15;
    #pragma unroll
    for (int ni = 0; ni < 4; ++ni) {
        const int gn = n0 + wc * 64 + ni * 16 + ocol;
        const float bv = bias[gn];
        #pragma unroll
        for (int mi = 0; mi < 4; ++mi) {
            const int gm = m0 + wr * 64 + mi * 16 + orow;
            float* po = out + (size_t)gm * NDIM + gn;
            #pragma unroll
            for (int r = 0; r < 4; ++r)
                po[(size_t)r * NDIM] = acc[mi][ni][r] + bv;
        }
    }
}

extern "C" void kernel_launch(void* const* d_in, const int* in_sizes, int n_in,
                              void* d_out, int out_size, void* d_ws, size_t ws_size,
                              hipStream_t stream)
{
    const float* x  = (const float*)d_in[0];
    const float* W  = (const float*)d_in[1];
    const float* bv = (const float*)d_in[2];
    float* out = (float*)d_out;

    bf16_t* Bm  = (bf16_t*)d_ws;                                   // 9*1152*128 bf16 = 2.65 MB
    float* bias = (float*)((char*)d_ws + (size_t)9 * KDIM * 128 * sizeof(bf16_t));

    build_wb<<<576, 256, 0, stream>>>(W, bv, Bm, bias);
    ind_gemm<<<1152, 256, 0, stream>>>(x, Bm, bias, out);
}